// Round 5
// baseline (725.845 us; speedup 1.0000x reference)
//
#include <hip/hip_runtime.h>
#include <math.h>

#define TB   64
#define TT   255
#define TIN  32
#define NH   256
#define NE   128
#define NK   255
#define NPAD 127

// ---- spectral conv2 params ----
// Circular DFT length 384: linear-conv support [-127,381] aliases only into
// t in [257,383] mod 384, so the needed window t in [0,255) is exact.
#define NF    384
#define NBINS 193          // NF/2+1
#define NFC   386          // interleaved re/im component rows (2*NBINS)
#define FCP   416          // fc padded to multiple of 32 (idft K)
#define HCH   64           // h-chunk size (4 chunks cover H=256)

typedef __attribute__((ext_vector_type(8))) short short8;
typedef __attribute__((ext_vector_type(4))) float float4v;

// ---- workspace layout (byte offsets) ----
#define WSB_WP1  0u            // 8,388,608  conv1 packed weights (dead after conv1)
#define WSB_Z    0u            // z (8192*255*4 = 8,355,840) aliases wp1
#define WSB_HF   8388608u      // hf 16,777,216 (alive through dft chunk 3)
#define WSB_HMID 8388608u      // hmid aliases hf (dead before mlp1)
#define WSB_W2S  25165824u     // 386*8192*4 = 12,648,448  spectral W2 chunk [fc][e*64+h_l]
#define WSB_HSP  37814272u     // 386*4096*4 =  6,324,224  spectral hbn chunk [fc][b*64+h_l]
#define WSB_ZSP  44138496u     // 386*8192*4 = 12,648,448  spectral z accumulator [fc][b*128+e]
#define WSB_BD   56786944u     // 386*256*4 = 395,264  forward basis (time)
#define WSB_BW   57182208u     // 386*256*4            weight basis (k)
#define WSB_BIT  57577472u     // 256*416*4 = 425,984  inverse basis, t-major [t][fc]
#define WSB_BN   58003456u     // 4 x 256 f32: sum1/sum2/sc/sh   (end 58,007,552)

// ---- output layout (float offsets) ----
#define O_AMP   0u
#define O_PHASE 8128u
#define O_FREQ  16320u
#define O_OFF   24448u

static __device__ __forceinline__ unsigned short f2bf(float f) {
  unsigned int u = __float_as_uint(f);
  unsigned int r = (u + 0x7FFFu + ((u >> 16) & 1u)) >> 16;
  return (unsigned short)r;
}
static __device__ __forceinline__ float bf2f(unsigned short s) {
  return __uint_as_float(((unsigned int)s) << 16);
}
static __device__ __forceinline__ short8 as_s8(uint4 v) {
  union { uint4 u; short8 s; } c; c.u = v; return c.s;
}

// 3-way bf16 split: x ~= h + l + m2 (24 mantissa bits captured)
static __device__ __forceinline__ void split3(float x, unsigned short& h,
                                              unsigned short& l, unsigned short& m2) {
  h = f2bf(x);
  float r1 = x - bf2f(h);
  l = f2bf(r1);
  m2 = f2bf(r1 - bf2f(l));
}

// 2-component staging (conv1 path): hi slots {0..3}^sw, lo slots {4..7}^sw
static __device__ __forceinline__ void stage8(unsigned int* __restrict__ U, int r,
                                              int p0, const float* __restrict__ v) {
  const int sw = r & 7;
  const int base = r * 32;
#pragma unroll
  for (int q = 0; q < 4; ++q) {
    float x0 = v[2 * q], x1 = v[2 * q + 1];
    unsigned short h0 = f2bf(x0), h1 = f2bf(x1);
    unsigned short l0 = f2bf(x0 - bf2f(h0)), l1 = f2bf(x1 - bf2f(h1));
    int p = p0 + q;
    U[base + ((((p >> 2) ^ sw) << 2) | (p & 3))] = (unsigned int)h0 | ((unsigned int)h1 << 16);
    U[base + (((((p >> 2) + 4) ^ sw) << 2) | (p & 3))] = (unsigned int)l0 | ((unsigned int)l1 << 16);
  }
}

// 3-component staging: hi/lo into U, 3rd component into U2's hi slots
static __device__ __forceinline__ void stage8_3(unsigned int* __restrict__ U,
                                                unsigned int* __restrict__ U2, int r,
                                                int p0, const float* __restrict__ v) {
  const int sw = r & 7;
  const int base = r * 32;
#pragma unroll
  for (int q = 0; q < 4; ++q) {
    unsigned short h0, l0, m0_, h1, l1, m1_;
    split3(v[2 * q], h0, l0, m0_);
    split3(v[2 * q + 1], h1, l1, m1_);
    int p = p0 + q;
    int shi = (((p >> 2) ^ sw) << 2) | (p & 3);
    int slo = ((((p >> 2) + 4) ^ sw) << 2) | (p & 3);
    U[base + shi] = (unsigned int)h0 | ((unsigned int)h1 << 16);
    U[base + slo] = (unsigned int)l0 | ((unsigned int)l1 << 16);
    U2[base + shi] = (unsigned int)m0_ | ((unsigned int)m1_ << 16);
  }
}
// single k-pair, 3-component (for transpose stagers)
static __device__ __forceinline__ void stage2_3(unsigned int* __restrict__ U,
                                                unsigned int* __restrict__ U2, int r,
                                                int p, float x0, float x1) {
  const int sw = r & 7;
  unsigned short h0, l0, m0_, h1, l1, m1_;
  split3(x0, h0, l0, m0_);
  split3(x1, h1, l1, m1_);
  int shi = (((p >> 2) ^ sw) << 2) | (p & 3);
  int slo = ((((p >> 2) + 4) ^ sw) << 2) | (p & 3);
  U[r * 32 + shi] = (unsigned int)h0 | ((unsigned int)h1 << 16);
  U[r * 32 + slo] = (unsigned int)l0 | ((unsigned int)l1 << 16);
  U2[r * 32 + shi] = (unsigned int)m0_ | ((unsigned int)m1_ << 16);
}
// fragment read: part 0 = hi, 1 = lo
static __device__ __forceinline__ short8 frag(const unsigned short* __restrict__ lds,
                                              int row, int quad, int part) {
  return *(const short8*)&lds[row * 64 + (((quad ^ (part << 2)) ^ (row & 7)) << 3)];
}
#define MF(a, b, c) __builtin_amdgcn_mfma_f32_16x16x32_bf16((a), (b), (c), 0, 0, 0)
// 6-term product: (ah+al+a2)(bh+bl+b2) minus O(2^-24) cross terms
#define MF6(accv, ahv, alv, a2v, bhv, blv, b2v) do {                              \
    accv = MF(ahv, bhv, accv);                                                    \
    accv = MF(ahv, blv, accv);                                                    \
    accv = MF(alv, bhv, accv);                                                    \
    accv = MF(alv, blv, accv);                                                    \
    accv = MF(ahv, b2v, accv);                                                    \
    accv = MF(a2v, bhv, accv);                                                    \
  } while (0)

// ---------------- small init kernels ----------------
__global__ __launch_bounds__(256) void bn_zero_k(float* __restrict__ bn) {
  bn[threadIdx.x] = 0.f;
  bn[256 + threadIdx.x] = 0.f;
}

// DFT basis tables (exact integer angle reduction).
// bd[2f][t]   =  cos(2*pi*f*t/384),  bd[2f+1][t] = -sin(...); col 255 zeroed (K pad)
// bw[2f][k]   =  cos(2*pi*f*(k-127)/384), bw[2f+1][k] = +sin(...); col 255 zeroed
// bi_t[t][fc]: fc=2f: w*cos(2*pi*f*t/384)/384, fc=2f+1: -w*sin(...)/384, w=2 (1 at f=0,192)
//              cols 386..415 zeroed (K pad for idft)
__global__ __launch_bounds__(256) void basis_init_k(float* __restrict__ bd,
                                                    float* __restrict__ bw,
                                                    float* __restrict__ bi_t) {
  const int m = blockIdx.x;          // 0..385 component row
  const int t = threadIdx.x;         // 0..255
  const int f = m >> 1, im = m & 1;
  const float C = 6.28318530717958647692f / 384.f;
  int r1 = (f * t) % 384;
  float th1 = C * (float)r1;
  float s1 = sinf(th1), c1 = cosf(th1);
  float vd = im ? -s1 : c1;
  bd[m * 256 + t] = (t == 255) ? 0.f : vd;
  float wgt = (f == 0 || f == 192) ? 1.f : 2.f;
  bi_t[t * FCP + m] = (im ? -s1 * wgt : c1 * wgt) * (1.f / 384.f);
  if (m < FCP - NFC) bi_t[t * FCP + NFC + m] = 0.f;
  int a = f * (t - 127);
  int r2 = a % 384; if (r2 < 0) r2 += 384;
  float th2 = C * (float)r2;
  float vw = im ? sinf(th2) : cosf(th2);
  bw[m * 256 + t] = (t == 255) ? 0.f : vw;
}

// ---------------- conv1 weight packing (hi/lo split) ----------------
__global__ __launch_bounds__(256) void pack1_k(const float* __restrict__ w1,
                                               unsigned int* __restrict__ wp1u) {
  __shared__ float tile[512][33];
  const int et = blockIdx.x, kc = blockIdx.y;
  const int kk0 = kc * 32, cnt = min(32, NK - kk0);
  const int tid = threadIdx.x;
  for (int idx = tid; idx < 512 * 32; idx += 256) {
    int row = idx >> 5, kl = idx & 31;
    if (kl < cnt) {
      int e_l = row >> 5, i_l = row & 31;
      tile[row][kl] = w1[(size_t)((et * 16 + e_l) * TIN + i_l) * NK + kk0 + kl];
    }
  }
  __syncthreads();
  const int lane = tid >> 2, jp = (tid & 3) * 2;
  const int row0 = (lane & 15) * 32 + (lane >> 4) * 8 + jp;
  for (int kl = 0; kl < cnt; ++kl) {
    float w0 = tile[row0][kl], w1v = tile[row0 + 1][kl];
    unsigned short h0 = f2bf(w0), h1 = f2bf(w1v);
    unsigned short l0 = f2bf(w0 - bf2f(h0)), l1 = f2bf(w1v - bf2f(h1));
    size_t base = (size_t)(kk0 + kl) * 8192 + et * 512 + tid;
    wp1u[base] = (unsigned int)h0 | ((unsigned int)h1 << 16);
    wp1u[base + 256] = (unsigned int)l0 | ((unsigned int)l1 << 16);
  }
}

// ---------------- conv1 MFMA (split-bf16 3-term, depth-3 B ring) --------------
#define C1_ROWS 384
__global__ __launch_bounds__(256, 2) void conv1_mfma(
    const float* __restrict__ s, const unsigned int* __restrict__ wp1u,
    const float* __restrict__ b1v, float* __restrict__ hf, float* __restrict__ bn) {
  __shared__ __align__(16) unsigned short Alds[C1_ROWS * 64];   // 49152 B
  const int th = blockIdx.x & 1, chg = blockIdx.x >> 1, b = blockIdx.y;
  const int tid = threadIdx.x, lane = tid & 63, wv = tid >> 6;
  const int quad = lane >> 4, l15 = lane & 15;
  const int tg = wv & 1, eg = wv >> 1;
  unsigned int* Au = (unsigned int*)Alds;

  for (int idx = tid; idx < C1_ROWS * 16; idx += 256) {
    int r = idx >> 4, p = idx & 15;
    int t = th * 128 + r - NPAD;
    float v0 = 0.f, v1 = 0.f;
    if (t >= 0 && t < TT) {
      const float* sp = &s[(size_t)(b * TT + t) * TIN + p * 2];
      v0 = sp[0]; v1 = sp[1];
    }
    unsigned short h0 = f2bf(v0), h1 = f2bf(v1);
    unsigned short l0 = f2bf(v0 - bf2f(h0)), l1 = f2bf(v1 - bf2f(h1));
    int sw = r & 7;
    Au[r * 32 + ((((p >> 2) ^ sw) << 2) | (p & 3))] = (unsigned int)h0 | ((unsigned int)h1 << 16);
    Au[r * 32 + (((((p >> 2) + 4) ^ sw) << 2) | (p & 3))] = (unsigned int)l0 | ((unsigned int)l1 << 16);
  }

#define LOADB1(buf, KK) do {                                                      \
    const uint4* _b = (const uint4*)(wp1u + (size_t)(KK) * 8192u) +               \
                      (chg * 4 + eg * 2) * 128;                                   \
    buf[0] = _b[lane];          buf[1] = _b[64 + lane];                           \
    buf[2] = _b[128 + lane];    buf[3] = _b[192 + lane];                          \
  } while (0)

#define MSTEP1(KK, buf) do {                                                      \
    short8 bh0 = as_s8(buf[0]), bl0 = as_s8(buf[1]);                              \
    short8 bh1 = as_s8(buf[2]), bl1 = as_s8(buf[3]);                              \
    _Pragma("unroll")                                                             \
    for (int mi = 0; mi < 4; ++mi) {                                              \
      const int row = tg * 64 + mi * 16 + l15 + (KK);                             \
      const int sw = row & 7;                                                     \
      short8 ah = *(const short8*)&Alds[row * 64 + ((quad ^ sw) << 3)];           \
      short8 al = *(const short8*)&Alds[row * 64 + (((quad ^ 4) ^ sw) << 3)];     \
      acc[mi][0] = MF(ah, bh0, acc[mi][0]);                                       \
      acc[mi][0] = MF(ah, bl0, acc[mi][0]);                                       \
      acc[mi][0] = MF(al, bh0, acc[mi][0]);                                       \
      acc[mi][1] = MF(ah, bh1, acc[mi][1]);                                       \
      acc[mi][1] = MF(ah, bl1, acc[mi][1]);                                       \
      acc[mi][1] = MF(al, bh1, acc[mi][1]);                                       \
    }                                                                             \
  } while (0)

  uint4 b0[4], b1x[4], b2x[4];
  LOADB1(b0, 0);
  LOADB1(b1x, 1);
  LOADB1(b2x, 2);
  __syncthreads();

  float4v acc[4][2];
#pragma unroll
  for (int mi = 0; mi < 4; ++mi)
#pragma unroll
    for (int ni = 0; ni < 2; ++ni) acc[mi][ni] = (float4v)(0.f);

  for (int kp = 0; kp < 84; ++kp) {
    const int kk = kp * 3;
    MSTEP1(kk, b0);     LOADB1(b0, kk + 3);
    MSTEP1(kk + 1, b1x); LOADB1(b1x, kk + 4);
    MSTEP1(kk + 2, b2x); LOADB1(b2x, kk + 5);
  }
  MSTEP1(252, b0);
  MSTEP1(253, b1x);
  MSTEP1(254, b2x);

  float s1[2] = {0.f, 0.f}, s2[2] = {0.f, 0.f};
#pragma unroll
  for (int mi = 0; mi < 4; ++mi) {
#pragma unroll
    for (int ni = 0; ni < 2; ++ni) {
      int ch = chg * 64 + (eg * 2 + ni) * 16 + l15;
      float bias = b1v[ch];
#pragma unroll
      for (int r = 0; r < 4; ++r) {
        int t = th * 128 + tg * 64 + mi * 16 + quad * 4 + r;
        if (t < TT) {
          float v = fmaxf(acc[mi][ni][r] + bias, 0.f);
          hf[(size_t)(b * 256 + t) * NH + ch] = v;
          s1[ni] += v; s2[ni] += v * v;
        }
      }
    }
  }
#pragma unroll
  for (int ni = 0; ni < 2; ++ni) {
    s1[ni] += __shfl_xor(s1[ni], 16);
    s1[ni] += __shfl_xor(s1[ni], 32);
    s2[ni] += __shfl_xor(s2[ni], 16);
    s2[ni] += __shfl_xor(s2[ni], 32);
    if (quad == 0) {
      int ch = chg * 64 + (eg * 2 + ni) * 16 + l15;
      atomicAdd(&bn[ch], s1[ni]);
      atomicAdd(&bn[256 + ch], s2[ni]);
    }
  }
#undef LOADB1
#undef MSTEP1
}

__global__ __launch_bounds__(256) void bn_final_k(const float* __restrict__ gamma,
                                                  const float* __restrict__ beta,
                                                  float* __restrict__ bn) {
  const int h = threadIdx.x;
  const float inv = 1.0f / (TB * TT);
  float m = bn[h] * inv;
  float var = bn[256 + h] * inv - m * m;
  float sc = gamma[h] / sqrtf(var + 1e-5f);
  bn[512 + h] = sc;
  bn[768 + h] = beta[h] - m * sc;
}

// =============== spectral conv2 — 6-term double-split MFMA GEMMs ==============
// All use 16x16x32 bf16 MFMA with 3-way operand splits (fp32-class accuracy),
// conv1's proven LDS swizzle/fragment scheme, both operands LDS-staged.

// W[fc][e*64+h_l] = sum_k bw[fc][k] * w2[e][h0c+h_l][k]. Tile 128m x 128n, K=256.
__global__ __launch_bounds__(256, 2) void w2prep_mfma(
    const float* __restrict__ w2, const float* __restrict__ bw,
    float* __restrict__ W, int h0c) {
  __shared__ __align__(16) unsigned short Alds[128 * 64];
  __shared__ __align__(16) unsigned short A2lds[128 * 64];
  __shared__ __align__(16) unsigned short Blds[128 * 64];
  __shared__ __align__(16) unsigned short B2lds[128 * 64];
  const int n0 = blockIdx.x * 128, m0 = blockIdx.y * 128;
  const int tid = threadIdx.x, lane = tid & 63, wv = tid >> 6;
  const int quad = lane >> 4, l15 = lane & 15;
  const int wm = wv >> 1, wn = wv & 1;
  unsigned int* Au = (unsigned int*)Alds;
  unsigned int* A2u = (unsigned int*)A2lds;
  unsigned int* Bu = (unsigned int*)Blds;
  unsigned int* B2u = (unsigned int*)B2lds;

  float4v acc[4][4];
#pragma unroll
  for (int i = 0; i < 4; ++i)
#pragma unroll
    for (int j = 0; j < 4; ++j) acc[i][j] = (float4v)(0.f);

  const int rA = tid >> 1, hfA = tid & 1;
  const int fcA = m0 + rA;
  const float* srcA = bw + fcA * 256;
  const int rB = tid >> 1, hfB = tid & 1;
  const int eB = (n0 + rB) >> 6, hlB = (n0 + rB) & 63;
  const float* srcB = w2 + ((size_t)(eB * NH + h0c + hlB)) * NK;

  for (int kk = 0; kk < 8; ++kk) {
    const int k0 = kk * 32;
    if (kk) __syncthreads();
    {   // A: basis rows, aligned float4 (stride 256 floats)
      float va[16];
      if (fcA < NFC) {
        const float4* s4 = (const float4*)(srcA + k0 + hfA * 16);
        *(float4*)(va + 0) = s4[0]; *(float4*)(va + 4) = s4[1];
        *(float4*)(va + 8) = s4[2]; *(float4*)(va + 12) = s4[3];
      } else {
#pragma unroll
        for (int q = 0; q < 16; ++q) va[q] = 0.f;
      }
      stage8_3(Au, A2u, rA, hfA * 8, va);
      stage8_3(Au, A2u, rA, hfA * 8 + 4, va + 8);
    }
    {   // B: w2 rows (stride 255 floats, scalar loads, k<NK guard)
      float vb[16];
#pragma unroll
      for (int q = 0; q < 16; ++q) {
        int k = k0 + hfB * 16 + q;
        vb[q] = (k < NK) ? srcB[k] : 0.f;
      }
      stage8_3(Bu, B2u, rB, hfB * 8, vb);
      stage8_3(Bu, B2u, rB, hfB * 8 + 4, vb + 8);
    }
    __syncthreads();
    short8 bh[4], bl[4], b2[4];
#pragma unroll
    for (int ni = 0; ni < 4; ++ni) {
      int rb = wn * 64 + ni * 16 + l15;
      bh[ni] = frag(Blds, rb, quad, 0);
      bl[ni] = frag(Blds, rb, quad, 1);
      b2[ni] = frag(B2lds, rb, quad, 0);
    }
#pragma unroll
    for (int mi = 0; mi < 4; ++mi) {
      int ra = wm * 64 + mi * 16 + l15;
      short8 ah = frag(Alds, ra, quad, 0);
      short8 al = frag(Alds, ra, quad, 1);
      short8 a2 = frag(A2lds, ra, quad, 0);
#pragma unroll
      for (int ni = 0; ni < 4; ++ni) MF6(acc[mi][ni], ah, al, a2, bh[ni], bl[ni], b2[ni]);
    }
  }
#pragma unroll
  for (int mi = 0; mi < 4; ++mi) {
    int fc0 = m0 + wm * 64 + mi * 16 + quad * 4;
#pragma unroll
    for (int ni = 0; ni < 4; ++ni) {
      int n = n0 + wn * 64 + ni * 16 + l15;
#pragma unroll
      for (int r = 0; r < 4; ++r) {
        if (fc0 + r < NFC) W[(size_t)(fc0 + r) * 8192 + n] = acc[mi][ni][r];
      }
    }
  }
}

// H[fc][b*64+h_l] = sum_t bd[fc][t] * (hf[b][t][h0c+h_l]*sc+sh). 128x128, K=256.
__global__ __launch_bounds__(256, 2) void dftH_mfma(
    const float* __restrict__ hf, const float* __restrict__ bn,
    const float* __restrict__ bd, float* __restrict__ H, int h0c) {
  __shared__ __align__(16) unsigned short Alds[128 * 64];
  __shared__ __align__(16) unsigned short A2lds[128 * 64];
  __shared__ __align__(16) unsigned short Blds[128 * 64];
  __shared__ __align__(16) unsigned short B2lds[128 * 64];
  const int n0 = blockIdx.x * 128, m0 = blockIdx.y * 128;
  const int b0 = n0 >> 6;
  const int tid = threadIdx.x, lane = tid & 63, wv = tid >> 6;
  const int quad = lane >> 4, l15 = lane & 15;
  const int wm = wv >> 1, wn = wv & 1;
  const int g = tid >> 6;
  unsigned int* Au = (unsigned int*)Alds;
  unsigned int* A2u = (unsigned int*)A2lds;
  unsigned int* Bu = (unsigned int*)Blds;
  unsigned int* B2u = (unsigned int*)B2lds;
  const float scL = bn[512 + h0c + lane];
  const float shL = bn[768 + h0c + lane];

  float4v acc[4][4];
#pragma unroll
  for (int i = 0; i < 4; ++i)
#pragma unroll
    for (int j = 0; j < 4; ++j) acc[i][j] = (float4v)(0.f);

  const int rA = tid >> 1, hfA = tid & 1;
  const int fcA = m0 + rA;
  const float* srcA = bd + fcA * 256;

  for (int kk = 0; kk < 8; ++kk) {
    const int k0 = kk * 32;
    if (kk) __syncthreads();
    {   // A: basis rows (aligned float4)
      float va[16];
      if (fcA < NFC) {
        const float4* s4 = (const float4*)(srcA + k0 + hfA * 16);
        *(float4*)(va + 0) = s4[0]; *(float4*)(va + 4) = s4[1];
        *(float4*)(va + 8) = s4[2]; *(float4*)(va + 12) = s4[3];
      } else {
#pragma unroll
        for (int q = 0; q < 16; ++q) va[q] = 0.f;
      }
      stage8_3(Au, A2u, rA, hfA * 8, va);
      stage8_3(Au, A2u, rA, hfA * 8 + 4, va + 8);
    }
    // B transpose-stage: rows n = b_l*64 + h(lane), k = t
#pragma unroll
    for (int i = 0; i < 8; ++i) {
      int combo = i * 4 + g;              // [0,32): (t-pair, b_l)
      int tp = combo >> 1, bl_ = combo & 1;
      int t0 = k0 + tp * 2;
      int b = b0 + bl_;
      float v0 = (t0 < TT)
          ? fmaf(hf[(size_t)(b * 256 + t0) * NH + h0c + lane], scL, shL) : 0.f;
      float v1 = (t0 + 1 < TT)
          ? fmaf(hf[(size_t)(b * 256 + t0 + 1) * NH + h0c + lane], scL, shL) : 0.f;
      stage2_3(Bu, B2u, bl_ * 64 + lane, tp, v0, v1);
    }
    __syncthreads();
    short8 bh[4], bl[4], b2[4];
#pragma unroll
    for (int ni = 0; ni < 4; ++ni) {
      int rb = wn * 64 + ni * 16 + l15;
      bh[ni] = frag(Blds, rb, quad, 0);
      bl[ni] = frag(Blds, rb, quad, 1);
      b2[ni] = frag(B2lds, rb, quad, 0);
    }
#pragma unroll
    for (int mi = 0; mi < 4; ++mi) {
      int ra = wm * 64 + mi * 16 + l15;
      short8 ah = frag(Alds, ra, quad, 0);
      short8 al = frag(Alds, ra, quad, 1);
      short8 a2 = frag(A2lds, ra, quad, 0);
#pragma unroll
      for (int ni = 0; ni < 4; ++ni) MF6(acc[mi][ni], ah, al, a2, bh[ni], bl[ni], b2[ni]);
    }
  }
#pragma unroll
  for (int mi = 0; mi < 4; ++mi) {
    int fc0 = m0 + wm * 64 + mi * 16 + quad * 4;
#pragma unroll
    for (int ni = 0; ni < 4; ++ni) {
      int n = n0 + wn * 64 + ni * 16 + l15;
#pragma unroll
      for (int r = 0; r < 4; ++r) {
        if (fc0 + r < NFC) H[(size_t)(fc0 + r) * 4096 + n] = acc[mi][ni][r];
      }
    }
  }
}

// Per-frequency complex GEMM as a real GEMM: A=[Hr|Hi] (K=128), B per ri-tile:
// ri=0 (Re): [Wr ; -Wi], ri=1 (Im): [Wi ; Wr]. out zsp[2f+ri][b*128+e] (+)=.
__global__ __launch_bounds__(256, 2) void fgemm_mfma(
    const float* __restrict__ H, const float* __restrict__ W,
    float* __restrict__ zsp, int first) {
  __shared__ __align__(16) unsigned short Alds[64 * 64];
  __shared__ __align__(16) unsigned short A2lds[64 * 64];
  __shared__ __align__(16) unsigned short Blds[128 * 64];
  __shared__ __align__(16) unsigned short B2lds[128 * 64];
  const int ri = blockIdx.x, f = blockIdx.y;
  const int tid = threadIdx.x, lane = tid & 63, wv = tid >> 6;
  const int quad = lane >> 4, l15 = lane & 15;
  const int wm = wv >> 1, wn = wv & 1;
  unsigned int* Au = (unsigned int*)Alds;
  unsigned int* A2u = (unsigned int*)A2lds;
  unsigned int* Bu = (unsigned int*)Blds;
  unsigned int* B2u = (unsigned int*)B2lds;

  float4v acc[2][4];
#pragma unroll
  for (int i = 0; i < 2; ++i)
#pragma unroll
    for (int j = 0; j < 4; ++j) acc[i][j] = (float4v)(0.f);

  const int rA = tid >> 2, qA = tid & 3;   // A: 64 rows(b) x 4 thr (8 k each)
  const int rB = tid >> 1, hB = tid & 1;   // B: 128 rows(e) x 2 thr (16 k each)

  for (int kk = 0; kk < 4; ++kk) {
    const int ca = kk >> 1;                // A comp: 0=Hr, 1=Hi
    const int hb = (kk & 1) * 32;          // h sub-block
    if (kk) __syncthreads();
    {   // A stage (aligned)
      float va[8];
      const float4* s4 = (const float4*)(H + (size_t)(2 * f + ca) * 4096 + rA * 64 + hb + qA * 8);
      *(float4*)(va + 0) = s4[0]; *(float4*)(va + 4) = s4[1];
      stage8_3(Au, A2u, rA, qA * 4, va);
    }
    {   // B stage with comp select + sign (aligned)
      const int cb = ri ^ (kk >> 1);       // 0=Wr, 1=Wi
      const int neg = (ri == 0 && kk >= 2);
      float vb[16];
      const float4* s4 = (const float4*)(W + (size_t)(2 * f + cb) * 8192 + rB * 64 + hb + hB * 16);
      *(float4*)(vb + 0) = s4[0]; *(float4*)(vb + 4) = s4[1];
      *(float4*)(vb + 8) = s4[2]; *(float4*)(vb + 12) = s4[3];
      if (neg) {
#pragma unroll
        for (int q = 0; q < 16; ++q) vb[q] = -vb[q];
      }
      stage8_3(Bu, B2u, rB, hB * 8, vb);
      stage8_3(Bu, B2u, rB, hB * 8 + 4, vb + 8);
    }
    __syncthreads();
    short8 bh[4], bl[4], b2[4];
#pragma unroll
    for (int ni = 0; ni < 4; ++ni) {
      int rb = wn * 64 + ni * 16 + l15;
      bh[ni] = frag(Blds, rb, quad, 0);
      bl[ni] = frag(Blds, rb, quad, 1);
      b2[ni] = frag(B2lds, rb, quad, 0);
    }
#pragma unroll
    for (int mi = 0; mi < 2; ++mi) {
      int ra = wm * 32 + mi * 16 + l15;
      short8 ah = frag(Alds, ra, quad, 0);
      short8 al = frag(Alds, ra, quad, 1);
      short8 a2 = frag(A2lds, ra, quad, 0);
#pragma unroll
      for (int ni = 0; ni < 4; ++ni) MF6(acc[mi][ni], ah, al, a2, bh[ni], bl[ni], b2[ni]);
    }
  }
  float* Z = zsp + (size_t)(2 * f + ri) * 8192;
#pragma unroll
  for (int mi = 0; mi < 2; ++mi) {
#pragma unroll
    for (int ni = 0; ni < 4; ++ni) {
      int e = wn * 64 + ni * 16 + l15;
#pragma unroll
      for (int r = 0; r < 4; ++r) {
        int b = wm * 32 + mi * 16 + quad * 4 + r;
        size_t off = (size_t)b * 128 + e;
        if (first) Z[off] = acc[mi][ni][r];
        else       Z[off] += acc[mi][ni][r];
      }
    }
  }
}

// z[be][t] = sum_fc zsp[fc][be] * bi_t[t][fc] + b2[e]. M=be(128-tiles), N=t, K=416.
__global__ __launch_bounds__(256, 2) void idft_mfma(
    const float* __restrict__ zsp, const float* __restrict__ bi_t,
    const float* __restrict__ b2, float* __restrict__ z) {
  __shared__ __align__(16) unsigned short Alds[128 * 64];
  __shared__ __align__(16) unsigned short A2lds[128 * 64];
  __shared__ __align__(16) unsigned short Blds[128 * 64];
  __shared__ __align__(16) unsigned short B2lds[128 * 64];
  const int n0 = blockIdx.x * 128, m0 = blockIdx.y * 128;
  const int tid = threadIdx.x, lane = tid & 63, wv = tid >> 6;
  const int quad = lane >> 4, l15 = lane & 15;
  const int wm = wv >> 1, wn = wv & 1;
  const int g = tid >> 6;
  unsigned int* Au = (unsigned int*)Alds;
  unsigned int* A2u = (unsigned int*)A2lds;
  unsigned int* Bu = (unsigned int*)Blds;
  unsigned int* B2u = (unsigned int*)B2lds;

  float4v acc[4][4];
#pragma unroll
  for (int i = 0; i < 4; ++i)
#pragma unroll
    for (int j = 0; j < 4; ++j) acc[i][j] = (float4v)(0.f);

  const int rB = tid >> 1, hB = tid & 1;

  for (int kk = 0; kk < 13; ++kk) {
    const int k0 = kk * 32;
    if (kk) __syncthreads();
    // A transpose-stage: rows be, k = fc
#pragma unroll
    for (int i = 0; i < 8; ++i) {
      int combo = i * 4 + g;
      int tp = combo >> 1, beh = combo & 1;
      int fc0 = k0 + tp * 2;
      int row = beh * 64 + lane;
      float v0 = (fc0 < NFC) ? zsp[(size_t)fc0 * 8192 + m0 + row] : 0.f;
      float v1 = (fc0 + 1 < NFC) ? zsp[(size_t)(fc0 + 1) * 8192 + m0 + row] : 0.f;
      stage2_3(Au, A2u, row, tp, v0, v1);
    }
    {   // B straight: bi_t rows t (aligned: 416 floats/row)
      float vb[16];
      const float4* s4 = (const float4*)(bi_t + (size_t)(n0 + rB) * FCP + k0 + hB * 16);
      *(float4*)(vb + 0) = s4[0]; *(float4*)(vb + 4) = s4[1];
      *(float4*)(vb + 8) = s4[2]; *(float4*)(vb + 12) = s4[3];
      stage8_3(Bu, B2u, rB, hB * 8, vb);
      stage8_3(Bu, B2u, rB, hB * 8 + 4, vb + 8);
    }
    __syncthreads();
    short8 bh[4], bl[4], b2[4];
#pragma unroll
    for (int ni = 0; ni < 4; ++ni) {
      int rb = wn * 64 + ni * 16 + l15;
      bh[ni] = frag(Blds, rb, quad, 0);
      bl[ni] = frag(Blds, rb, quad, 1);
      b2[ni] = frag(B2lds, rb, quad, 0);
    }
#pragma unroll
    for (int mi = 0; mi < 4; ++mi) {
      int ra = wm * 64 + mi * 16 + l15;
      short8 ah = frag(Alds, ra, quad, 0);
      short8 al = frag(Alds, ra, quad, 1);
      short8 a2 = frag(A2lds, ra, quad, 0);
#pragma unroll
      for (int ni = 0; ni < 4; ++ni) MF6(acc[mi][ni], ah, al, a2, bh[ni], bl[ni], b2[ni]);
    }
  }
#pragma unroll
  for (int mi = 0; mi < 4; ++mi) {
#pragma unroll
    for (int ni = 0; ni < 4; ++ni) {
      int t = n0 + wn * 64 + ni * 16 + l15;
#pragma unroll
      for (int r = 0; r < 4; ++r) {
        int be = m0 + wm * 64 + mi * 16 + quad * 4 + r;
        if (t < TT) z[(size_t)be * TT + t] = acc[mi][ni][r] + b2[be & 127];
      }
    }
  }
}

// ---------------- MLP layer 1 (fp32 — phase-critical, kept exact) -------------
__global__ __launch_bounds__(256) void mlp1_k(const float* __restrict__ z,
                                              const float* __restrict__ pw1,
                                              const float* __restrict__ pb1,
                                              float* __restrict__ hmid) {
  const int TC = 128;
  __shared__ float zl[TC * 68];
  __shared__ float pl[TC * 68];
  const int c = blockIdx.y, h0 = blockIdx.x * 64, tid = threadIdx.x;
  const int h4 = tid & 15, b4 = tid >> 4;
  float acc[4][4];
#pragma unroll
  for (int a = 0; a < 4; ++a)
#pragma unroll
    for (int bb = 0; bb < 4; ++bb) acc[a][bb] = 0.f;
  for (int t0 = 0; t0 < TT; t0 += TC) {
    const int tc = min(TC, TT - t0);
    __syncthreads();
    for (int idx = tid; idx < 64 * tc; idx += 256) {
      int r = idx / tc, t = idx - r * tc;
      zl[t * 68 + r] = z[(size_t)(r * NE + c) * TT + t0 + t];
      pl[t * 68 + r] = pw1[(size_t)(c * NH + h0 + r) * TT + t0 + t];
    }
    __syncthreads();
    for (int t = 0; t < tc; ++t) {
      float4 zv = *(const float4*)&zl[t * 68 + b4 * 4];
      float4 pv = *(const float4*)&pl[t * 68 + h4 * 4];
      float zz[4] = {zv.x, zv.y, zv.z, zv.w};
      float pp[4] = {pv.x, pv.y, pv.z, pv.w};
#pragma unroll
      for (int a = 0; a < 4; ++a)
#pragma unroll
        for (int bb = 0; bb < 4; ++bb) acc[a][bb] = fmaf(pp[a], zz[bb], acc[a][bb]);
    }
  }
#pragma unroll
  for (int a = 0; a < 4; ++a) {
    int hh = h0 + h4 * 4 + a;
    float bias = pb1[c * NH + hh];
#pragma unroll
    for (int bb = 0; bb < 4; ++bb) {
      int bidx = b4 * 4 + bb;
      float v = acc[a][bb] + bias;
      hmid[(size_t)(bidx * NE + c) * NH + hh] = fmaxf(v, 0.f);
    }
  }
}

// ---------------- MLP layer 2 + atan2 ----------------
__global__ __launch_bounds__(256) void mlp2_k(const float* __restrict__ hmid,
                                              const float* __restrict__ pw2,
                                              const float* __restrict__ pb2,
                                              float* __restrict__ out) {
  const int tid = threadIdx.x, lane = tid & 63, wv = tid >> 6;
  const int p = blockIdx.x * 4 + wv;
  const int b = p >> 7, c = p & 127;
  const float4 hv = *(const float4*)&hmid[(size_t)(b * NE + c) * NH + lane * 4];
  const float4 p0 = *(const float4*)&pw2[(size_t)(c * 2 + 0) * NH + lane * 4];
  const float4 p1 = *(const float4*)&pw2[(size_t)(c * 2 + 1) * NH + lane * 4];
  float s0 = hv.x * p0.x + hv.y * p0.y + hv.z * p0.z + hv.w * p0.w;
  float s1 = hv.x * p1.x + hv.y * p1.y + hv.z * p1.z + hv.w * p1.w;
#pragma unroll
  for (int off = 32; off; off >>= 1) {
    s0 += __shfl_down(s0, off);
    s1 += __shfl_down(s1, off);
  }
  if (lane == 0) {
    float a0 = s0 + pb2[c * 2 + 0];
    float a1 = s1 + pb2[c * 2 + 1];
    out[O_PHASE + b * NE + c] = atan2f(a1, a0);
  }
}

// ---------------- amplitude (Parseval) + constant frequency ----------------
__global__ __launch_bounds__(256) void amp_k(const float* __restrict__ z,
                                             float* __restrict__ out) {
  const int tid = threadIdx.x, lane = tid & 63, wv = tid >> 6;
  const int b = blockIdx.x, c = blockIdx.y * 4 + wv;
  const float* row = z + (size_t)(b * NE + c) * TT;
  float s1 = 0.f, s2 = 0.f;
  for (int idx = lane; idx < TT; idx += 64) {
    float v = row[idx];
    s1 += v; s2 += v * v;
  }
#pragma unroll
  for (int off = 32; off; off >>= 1) {
    s1 += __shfl_down(s1, off);
    s2 += __shfl_down(s2, off);
  }
  if (lane == 0 && c >= 1) {
    float P = 0.5f * (255.f * s2 + s1 * s1);
    out[O_AMP + b * 127 + (c - 1)] = 2.f * sqrtf(P) / 255.f;
    out[O_FREQ + b * 127 + (c - 1)] = (float)c / 255.f;
  }
}

// ---------------- offset: real rfft spectrum of channel 0 ----------------
__global__ __launch_bounds__(128) void offset_k(const float* __restrict__ z,
                                                float* __restrict__ out) {
  __shared__ float zr[TT];
  __shared__ float ct[TT];
  const int b = blockIdx.x, tid = threadIdx.x;
  for (int idx = tid; idx < TT; idx += 128) {
    zr[idx] = z[(size_t)(b * NE + 0) * TT + idx];
    ct[idx] = cosf(6.283185307179586f * (float)idx / 255.f);
  }
  __syncthreads();
  const int f = tid;
  float s = 0.f;
  int m = 0;
  for (int t = 0; t < TT; ++t) {
    s += zr[t] * ct[m];
    m += f; if (m >= TT) m -= TT;
  }
  out[O_OFF + b * NE + f] = s / 255.f;
}

extern "C" void kernel_launch(void* const* d_in, const int* in_sizes, int n_in,
                              void* d_out, int out_size, void* d_ws, size_t ws_size,
                              hipStream_t stream) {
  (void)in_sizes; (void)n_in; (void)out_size; (void)ws_size;
  const float* s       = (const float*)d_in[0];
  const float* conv1_w = (const float*)d_in[1];
  const float* conv1_b = (const float*)d_in[2];
  const float* bn_g    = (const float*)d_in[3];
  const float* bn_b    = (const float*)d_in[4];
  const float* conv2_w = (const float*)d_in[5];
  const float* conv2_b = (const float*)d_in[6];
  const float* pw1     = (const float*)d_in[7];
  const float* pb1     = (const float*)d_in[8];
  const float* pw2     = (const float*)d_in[9];
  const float* pb2     = (const float*)d_in[10];
  float* out = (float*)d_out;
  char* ws   = (char*)d_ws;

  unsigned int* wp1u = (unsigned int*)(ws + WSB_WP1);
  float* z    = (float*)(ws + WSB_Z);      // aliases wp1 (dead after conv1)
  float* hf   = (float*)(ws + WSB_HF);
  float* hmid = (float*)(ws + WSB_HMID);   // aliases hf (dead after dftH)
  float* W2s  = (float*)(ws + WSB_W2S);
  float* Hs   = (float*)(ws + WSB_HSP);
  float* zsp  = (float*)(ws + WSB_ZSP);
  float* bd   = (float*)(ws + WSB_BD);
  float* bwt  = (float*)(ws + WSB_BW);
  float* bit  = (float*)(ws + WSB_BIT);
  float* bn   = (float*)(ws + WSB_BN);

  bn_zero_k<<<1, 256, 0, stream>>>(bn);
  basis_init_k<<<NFC, 256, 0, stream>>>(bd, bwt, bit);
  pack1_k<<<dim3(16, 8), 256, 0, stream>>>(conv1_w, wp1u);

  conv1_mfma<<<dim3(8, TB), 256, 0, stream>>>(s, wp1u, conv1_b, hf, bn);
  bn_final_k<<<1, 256, 0, stream>>>(bn_g, bn_b, bn);

  // spectral conv2, h-chunked (4 x 64 channels), all 6-term MFMA
  for (int c = 0; c < 4; ++c) {
    w2prep_mfma<<<dim3(64, 4), 256, 0, stream>>>(conv2_w, bwt, W2s, c * HCH);
    dftH_mfma<<<dim3(32, 4), 256, 0, stream>>>(hf, bn, bd, Hs, c * HCH);
    fgemm_mfma<<<dim3(2, NBINS), 256, 0, stream>>>(Hs, W2s, zsp, c == 0 ? 1 : 0);
  }
  idft_mfma<<<dim3(2, 64), 256, 0, stream>>>(zsp, bit, conv2_b, z);

  mlp1_k<<<dim3(4, NE), 256, 0, stream>>>(z, pw1, pb1, hmid);
  mlp2_k<<<TB * NE / 4, 256, 0, stream>>>(hmid, pw2, pb2, out);
  amp_k<<<dim3(TB, 32), 256, 0, stream>>>(z, out);
  offset_k<<<TB, 128, 0, stream>>>(z, out);
}